// Round 8
// baseline (226.350 us; speedup 1.0000x reference)
//
#include <hip/hip_runtime.h>
#include <hip/hip_bf16.h>
#include <hip/hip_fp16.h>

#define D_IN  128
#define D_HID 16
#define N_CLS 2
#define NPB   256          // nodes per bucket (bucket = dst >> 8)
#define MAXB  512          // max buckets (N <= 131072)
#define TILE  4096         // edges per k_part workgroup (512 thr x 8) -- TLP over run length
#define XROW  136          // padded LDS row stride (shorts)
#define LCAP  10496        // LDS edge slots in k_sortd (41 KB); bench cnt ~ 8.2K

#define FE 0   // edge_index storage: 0 = int32, 1 = int64

typedef short bf16x8 __attribute__((ext_vector_type(8)));
typedef float f32x4  __attribute__((ext_vector_type(4)));

__device__ __forceinline__ unsigned short f2bf(float f) {   // RNE float->bf16
    unsigned int u = __float_as_uint(f);
    u += 0x7FFFu + ((u >> 16) & 1u);
    return (unsigned short)(u >> 16);
}

template<bool I64>
__device__ __forceinline__ int lde(const void* p, size_t i) {
    if constexpr (I64) return (int)((const long long*)p)[i];
    else               return ((const int*)p)[i];
}

// ---------------- edge dtype detection (fallback path only) ----------------
__global__ void k_detect(const int* __restrict__ ev, int* __restrict__ flags) {
    __shared__ int sE;
    if (threadIdx.x == 0) sE = 0;
    __syncthreads();
    if (ev[2 * threadIdx.x + 1] != 0) atomicOr(&sE, 1);
    __syncthreads();
    if (threadIdx.x == 0) flags[FE] = sE ? 0 : 1;
}

// ---------------- pass 1: LDS-staged partition by bucket (fixed-cap regions) ----------------
template<bool I64>
__device__ __forceinline__ void part_body(
        const void* __restrict__ ei, unsigned int* __restrict__ gcur,
        unsigned int* __restrict__ staged, int E, int cap,
        unsigned int* sbuf, unsigned short* bbuf,
        int* hist, int* lbase, int* gb, int* wsum) {
    int tid = threadIdx.x;
    int t0 = blockIdx.x * TILE;

    hist[tid] = 0;
    __syncthreads();

    int myB[8]; unsigned int myP[8]; int myR[8];
#pragma unroll
    for (int k = 0; k < 8; ++k) {
        int e = t0 + k * 512 + tid;
        if (e < E) {
            int s = lde<I64>(ei, (size_t)e);
            int d = lde<I64>(ei, (size_t)E + e);
            int b = d >> 8;
            myB[k] = b;
            myP[k] = ((unsigned int)s << 8) | (unsigned int)(d & 255);
            myR[k] = atomicAdd(&hist[b], 1);
        } else myB[k] = -1;
    }
    __syncthreads();

    // shuffle-based scan over MAXB=512 counts
    int v = hist[tid];
    int lane = tid & 63, wv = tid >> 6;
    int s = v;
#pragma unroll
    for (int m = 1; m < 64; m <<= 1) {
        int t = __shfl_up(s, m, 64);
        if (lane >= m) s += t;
    }
    if (lane == 63) wsum[wv] = s;
    __syncthreads();
    int woff = 0;
#pragma unroll
    for (int w = 0; w < 8; ++w) if (w < wv) woff += wsum[w];
    int excl = s + woff - v;
    lbase[tid] = excl;
    int gb_ = 0;
    if (v > 0) gb_ = (int)atomicAdd(&gcur[tid], (unsigned int)v);  // relative base
    gb[tid] = gb_;
    __syncthreads();

#pragma unroll
    for (int k = 0; k < 8; ++k) {
        if (myB[k] >= 0) {
            int pos = lbase[myB[k]] + myR[k];
            sbuf[pos] = myP[k];
            bbuf[pos] = (unsigned short)myB[k];
        }
    }
    __syncthreads();

    int tot = lbase[MAXB - 1] + hist[MAXB - 1];
    for (int i = tid; i < tot; i += 512) {
        int b = bbuf[i];
        int rel = gb[b] + (i - lbase[b]);
        if (rel < cap)                           // overflow guard (degenerate inputs only)
            staged[(size_t)b * cap + rel] = sbuf[i];
    }
}

__global__ __launch_bounds__(512) void k_part(
        const void* __restrict__ ei, unsigned int* __restrict__ gcur,
        unsigned int* __restrict__ staged, int E, int cap) {
    __shared__ unsigned int sbuf[TILE];       // 16 KB
    __shared__ unsigned short bbuf[TILE];     // 8 KB
    __shared__ int hist[MAXB], lbase[MAXB], gb[MAXB];  // 6 KB
    __shared__ int wsum[8];
    __shared__ int sI64;
    int tid = threadIdx.x;
    if (tid == 0) sI64 = 1;
    __syncthreads();
    if (tid < 256 && 2 * tid + 1 < 2 * E && ((const int*)ei)[2 * tid + 1] != 0) sI64 = 0;
    __syncthreads();
    if (sI64) part_body<true >(ei, gcur, staged, E, cap, sbuf, bbuf, hist, lbase, gb, wsum);
    else      part_body<false>(ei, gcur, staged, E, cap, sbuf, bbuf, hist, lbase, gb, wsum);
}

// ---------------- pass 2: per-bucket counting sort by dst, 2 blocks/bucket ----------------
// grid (nb, 2): both blocks histogram the full bucket (LDS-staged read); each block
// scatters only its 128-dst half -> halved serial scatter, 2x TLP. Appends a SENTINEL
// self-edge per dst so every dst is a uniform run of deg+1 edges. Layout identical to
// the single-block version.
__global__ __launch_bounds__(512) void k_sortd(
        const unsigned int* __restrict__ staged, const unsigned int* __restrict__ gcur,
        unsigned int* __restrict__ staged2, unsigned int* __restrict__ dmeta,
        float* __restrict__ dinv, int cap, int N) {
    __shared__ unsigned int ebuf[LCAP];       // 41 KB
    __shared__ unsigned int h[NPB];
    __shared__ unsigned int cur[NPB];
    __shared__ int wsum[4];
    int tid = threadIdx.x, b = blockIdx.x;
    int half = blockIdx.y;                    // 0: dsts 0..127, 1: dsts 128..255
    long long s0 = (long long)b * cap;
    int cnt = (int)gcur[b];
    if (cnt > cap - NPB) cnt = cap - NPB;     // leave room for 256 sentinels
    bool inL = cnt <= LCAP;
    if (tid < NPB) h[tid] = 0u;
    __syncthreads();
    for (int i = tid; i < cnt; i += 512) {
        unsigned int p = staged[s0 + i];
        if (inL) ebuf[i] = p;
        atomicAdd(&h[p & 255], 1u);
    }
    __syncthreads();
    int v = 0, sIncl = 0;
    int lane = tid & 63, wv = tid >> 6;
    if (tid < NPB) {
        v = (int)h[tid];
        sIncl = v;
#pragma unroll
        for (int m = 1; m < 64; m <<= 1) {
            int t = __shfl_up(sIncl, m, 64);
            if (lane >= m) sIncl += t;
        }
        if (lane == 63) wsum[wv] = sIncl;
    }
    __syncthreads();
    if (tid < NPB) {
        int woff = 0;
#pragma unroll
        for (int w = 0; w < 4; ++w) if (w < wv) woff += wsum[w];
        int excl = sIncl + woff - v;
        int start = excl + tid;                  // +tid: one reserved sentinel slot per prior dst
        cur[tid] = (unsigned int)start;
        if ((tid >> 7) == half) {                // own half only: metadata + dinv
            int node = b * NPB + tid;
            dmeta[node] = ((unsigned int)start << 16) | (unsigned int)v;  // start<<16 | deg
            if (node < N) dinv[node] = rsqrtf((float)(v + 1));            // +1 self loop
        }
    }
    __syncthreads();
    for (int i = tid; i < cnt; i += 512) {
        unsigned int p = inL ? ebuf[i] : staged[s0 + i];
        int dl = (int)(p & 255);
        if ((dl >> 7) == half) {                 // scatter own half only
            unsigned int r = atomicAdd(&cur[dl], 1u);
            staged2[s0 + r] = p;
        }
    }
    __syncthreads();
    if (tid < NPB && (tid >> 7) == half) {
        unsigned int pos = cur[tid];             // = start + deg
        int node = b * NPB + tid;
        if ((int)pos < cap)
            staged2[s0 + pos] = ((unsigned int)node << 8) | (unsigned int)tid;  // sentinel self
    }
}

// ---------------- layer 1 GEMM via MFMA (split-bf16, 3 mfma/chunk ~ fp32 acc) ----------------
// hi via truncation (1 shift), lo via RNE of exact residual: err ~2^-16 rel, negligible.
__global__ __launch_bounds__(256) void k_gemm1m(
        const float* __restrict__ x, const float* __restrict__ W1,
        const float* __restrict__ dinv, __half* __restrict__ g1h, int n) {
    __shared__ short xhi[64 * XROW];
    __shared__ short xlo[64 * XROW];
    __shared__ short whi[16 * XROW];
    __shared__ short wlo[16 * XROW];
    int tid = threadIdx.x;
    int node0 = blockIdx.x * 64;

    for (int i = tid; i < D_IN * D_HID; i += 256) {
        int k = i >> 4, f = i & 15;
        float v = W1[i];
        unsigned short h = f2bf(v);
        float fh = __uint_as_float(((unsigned int)h) << 16);
        whi[f * XROW + k] = (short)h;
        wlo[f * XROW + k] = (short)f2bf(v - fh);
    }
    int limFlat = (n - node0) * D_IN;
#pragma unroll
    for (int it = 0; it < 8; ++it) {
        int flat = it * 1024 + tid * 4;
        float4 v = make_float4(0.f, 0.f, 0.f, 0.f);
        if (flat < limFlat) v = *(const float4*)(x + (size_t)node0 * D_IN + flat);
        int row = flat >> 7, k = flat & 127;
        unsigned int u0 = __float_as_uint(v.x), u1 = __float_as_uint(v.y);
        unsigned int u2 = __float_as_uint(v.z), u3 = __float_as_uint(v.w);
        unsigned short l0 = f2bf(v.x - __uint_as_float(u0 & 0xFFFF0000u));
        unsigned short l1 = f2bf(v.y - __uint_as_float(u1 & 0xFFFF0000u));
        unsigned short l2 = f2bf(v.z - __uint_as_float(u2 & 0xFFFF0000u));
        unsigned short l3 = f2bf(v.w - __uint_as_float(u3 & 0xFFFF0000u));
        int o = row * XROW + k;
        *(uint2*)(&xhi[o]) = make_uint2((u0 >> 16) | (u1 & 0xFFFF0000u),
                                        (u2 >> 16) | (u3 & 0xFFFF0000u));
        *(uint2*)(&xlo[o]) = make_uint2((unsigned int)l0 | ((unsigned int)l1 << 16),
                                        (unsigned int)l2 | ((unsigned int)l3 << 16));
    }
    __syncthreads();

    int w = tid >> 6, L = tid & 63;
    int m = L & 15, q = L >> 4;
    const short* axh = &xhi[(w * 16 + m) * XROW + q * 8];
    const short* axl = &xlo[(w * 16 + m) * XROW + q * 8];
    const short* bwh = &whi[m * XROW + q * 8];
    const short* bwl = &wlo[m * XROW + q * 8];
    f32x4 acc = {0.f, 0.f, 0.f, 0.f};
#pragma unroll
    for (int c = 0; c < 4; ++c) {
        bf16x8 ah = *(const bf16x8*)(axh + c * 32);
        bf16x8 al = *(const bf16x8*)(axl + c * 32);
        bf16x8 bh = *(const bf16x8*)(bwh + c * 32);
        bf16x8 bl = *(const bf16x8*)(bwl + c * 32);
        acc = __builtin_amdgcn_mfma_f32_16x16x32_bf16(ah, bh, acc, 0, 0, 0);
        acc = __builtin_amdgcn_mfma_f32_16x16x32_bf16(ah, bl, acc, 0, 0, 0);
        acc = __builtin_amdgcn_mfma_f32_16x16x32_bf16(al, bh, acc, 0, 0, 0);
    }
    int nodeB = node0 + w * 16 + q * 4;
#pragma unroll
    for (int r = 0; r < 4; ++r) {
        int node = nodeB + r;
        if (node < n) g1h[(size_t)node * D_HID + m] = __float2half(dinv[node] * acc[r]);
    }
}

// ---------------- layer-1 aggregation: clamped straight-line batched gathers ----------------
__global__ __launch_bounds__(256) void k_agg1w(
        const unsigned int* __restrict__ staged2, const unsigned int* __restrict__ dmeta,
        const __half* __restrict__ g1h,
        const float* __restrict__ b1, const float* __restrict__ W2,
        float2* __restrict__ g2, int N, int cap) {
    int tid = threadIdx.x, b = blockIdx.x, by = blockIdx.y;
    long long s0 = (long long)b * cap;
    int lane = tid & 63;
    int f2 = lane & 7;
    int e8 = lane >> 3;
    int wid = (by << 2) + (tid >> 6);        // wave id in bucket: 0..31
    const __half2* g1h2 = (const __half2*)g1h;
    int f0 = f2 * 2;
    float b10 = b1[f0], b11 = b1[f0 + 1];
    float w00 = W2[f0 * N_CLS + 0], w01 = W2[f0 * N_CLS + 1];
    float w10 = W2[(f0 + 1) * N_CLS + 0], w11 = W2[(f0 + 1) * N_CLS + 1];
    unsigned int md[8];
#pragma unroll
    for (int k = 0; k < 8; ++k) md[k] = dmeta[b * NPB + wid + (k << 5)];
#pragma unroll 2
    for (int k = 0; k < 8; ++k) {
        int node = b * NPB + wid + (k << 5);
        const unsigned int* sp = staged2 + s0 + (md[k] >> 16);
        int cnt = (int)(md[k] & 0xFFFFu) + 1;    // + sentinel self edge
        float ax = 0.f, ay = 0.f;
        for (int base = 0; base < cnt; base += 64) {
            unsigned int pe[8];
#pragma unroll
            for (int j = 0; j < 8; ++j) {        // phase 1: 8 independent loads (clamped)
                int idx = base + (j << 3) + e8;
                int c = idx < cnt ? idx : cnt - 1;
                pe[j] = sp[c];
            }
#pragma unroll
            for (int j = 0; j < 8; ++j) {        // phase 2+3: 8 independent gathers, masked acc
                int idx = base + (j << 3) + e8;
                float2 t = __half22float2(g1h2[(size_t)(pe[j] >> 8) * 8 + f2]);
                if (idx < cnt) { ax += t.x; ay += t.y; }
            }
        }
        // reduce over edge slots (lane bits 3..5)
        ax += __shfl_xor(ax, 8, 64);  ay += __shfl_xor(ay, 8, 64);
        ax += __shfl_xor(ax, 16, 64); ay += __shfl_xor(ay, 16, 64);
        ax += __shfl_xor(ax, 32, 64); ay += __shfl_xor(ay, 32, 64);
        float di = rsqrtf((float)cnt);           // == dinv[node] (cnt = deg+1)
        float r0 = fmaxf(b10 + di * ax, 0.f);
        float r1 = fmaxf(b11 + di * ay, 0.f);
        float c0 = r0 * w00 + r1 * w10;
        float c1 = r0 * w01 + r1 * w11;
        // reduce over feature pairs (lane bits 0..2)
        c0 += __shfl_xor(c0, 1, 64); c1 += __shfl_xor(c1, 1, 64);
        c0 += __shfl_xor(c0, 2, 64); c1 += __shfl_xor(c1, 2, 64);
        c0 += __shfl_xor(c0, 4, 64); c1 += __shfl_xor(c1, 4, 64);
        if (lane == 0 && node < N) g2[node] = make_float2(di * c0, di * c1);
    }
}

// ---------------- layer-2 aggregation + log_softmax: clamped full-wave gather ----------------
__global__ __launch_bounds__(256) void k_agg2w(
        const unsigned int* __restrict__ staged2, const unsigned int* __restrict__ dmeta,
        const float2* __restrict__ g2,
        const float* __restrict__ b2, float2* __restrict__ out, int N, int cap) {
    int tid = threadIdx.x, b = blockIdx.x, by = blockIdx.y;
    long long s0 = (long long)b * cap;
    int lane = tid & 63;
    int wid = (by << 2) + (tid >> 6);        // 0..31
    float bb0 = b2[0], bb1 = b2[1];
    unsigned int md[8];
#pragma unroll
    for (int k = 0; k < 8; ++k) md[k] = dmeta[b * NPB + wid + (k << 5)];
#pragma unroll 2
    for (int k = 0; k < 8; ++k) {
        int node = b * NPB + wid + (k << 5);
        const unsigned int* sp = staged2 + s0 + (md[k] >> 16);
        int cnt = (int)(md[k] & 0xFFFFu) + 1;    // + sentinel self edge
        float a0 = 0.f, a1 = 0.f;
        for (int base = 0; base < cnt; base += 64) {
            int idx = base + lane;
            int c = idx < cnt ? idx : cnt - 1;
            unsigned int p = sp[c];
            float2 t = g2[p >> 8];
            if (idx < cnt) { a0 += t.x; a1 += t.y; }
        }
#pragma unroll
        for (int mm = 1; mm < 64; mm <<= 1) {
            a0 += __shfl_xor(a0, mm, 64);
            a1 += __shfl_xor(a1, mm, 64);
        }
        if (lane == 0 && node < N) {
            float di = rsqrtf((float)cnt);       // == dinv[node]
            float v0 = bb0 + di * a0;
            float v1 = bb1 + di * a1;
            float mx = fmaxf(v0, v1);
            float lse = mx + logf(expf(v0 - mx) + expf(v1 - mx));
            out[node] = make_float2(v0 - lse, v1 - lse);
        }
    }
}

// =================== fallback (atomic path, if ws too small) ===================
__global__ void fb_deg_init(unsigned int* __restrict__ deg, int n) {
    int i = blockIdx.x * blockDim.x + threadIdx.x;
    if (i < n) deg[i] = 1u;
}
template<bool I64>
__global__ void fb_deg_count(const void* __restrict__ ei, unsigned int* __restrict__ deg,
                             int E, const int* __restrict__ flags) {
    if (flags[FE] != (int)I64) return;
    int e = blockIdx.x * blockDim.x + threadIdx.x;
    if (e < E) atomicAdd(&deg[lde<I64>(ei, (size_t)E + e)], 1u);
}
__global__ void fb_dinv_inplace(float* __restrict__ dinv, int n) {
    int i = blockIdx.x * blockDim.x + threadIdx.x;
    if (i < n) {
        unsigned int u = ((const unsigned int*)dinv)[i];
        dinv[i] = rsqrtf((float)u);
    }
}
__global__ void fb_a1_init(const float* __restrict__ h1, const float* __restrict__ dinv,
                           const float* __restrict__ b1, float* __restrict__ a1, int n) {
    int tid = blockIdx.x * blockDim.x + threadIdx.x;
    if (tid >= n * D_HID) return;
    int node = tid >> 4, f = tid & 15;
    float di = dinv[node];
    a1[tid] = b1[f] + di * di * h1[tid];
}
template<bool I64>
__global__ void fb_agg1(const void* __restrict__ ei, const float* __restrict__ dinv,
                        const float* __restrict__ h1, float* __restrict__ a1,
                        int E, const int* __restrict__ flags) {
    if (flags[FE] != (int)I64) return;
    int tid = blockIdx.x * blockDim.x + threadIdx.x;
    int e = tid >> 4, f = tid & 15;
    if (e >= E) return;
    int s = lde<I64>(ei, (size_t)e);
    int d = lde<I64>(ei, (size_t)E + e);
    float norm = dinv[s] * dinv[d];
    atomicAdd(&a1[(size_t)d * D_HID + f], h1[(size_t)s * D_HID + f] * norm);
}
__global__ void fb_relu_gemm2(const float* __restrict__ a1, const float* __restrict__ W2,
                              float* __restrict__ h2, int n) {
    int node = blockIdx.x * blockDim.x + threadIdx.x;
    if (node >= n) return;
    float c0 = 0.f, c1 = 0.f;
    const float* row = a1 + (size_t)node * D_HID;
#pragma unroll
    for (int f = 0; f < D_HID; ++f) {
        float r = fmaxf(row[f], 0.f);
        c0 += r * W2[f * N_CLS + 0];
        c1 += r * W2[f * N_CLS + 1];
    }
    h2[(size_t)node * 2 + 0] = c0;
    h2[(size_t)node * 2 + 1] = c1;
}
__global__ void fb_a2_init(const float* __restrict__ h2, const float* __restrict__ dinv,
                           const float* __restrict__ b2, float* __restrict__ a2, int n) {
    int tid = blockIdx.x * blockDim.x + threadIdx.x;
    if (tid >= n * N_CLS) return;
    int node = tid >> 1, c = tid & 1;
    float di = dinv[node];
    a2[tid] = b2[c] + di * di * h2[tid];
}
template<bool I64>
__global__ void fb_agg2(const void* __restrict__ ei, const float* __restrict__ dinv,
                        const float* __restrict__ h2, float* __restrict__ a2,
                        int E, const int* __restrict__ flags) {
    if (flags[FE] != (int)I64) return;
    int e = blockIdx.x * blockDim.x + threadIdx.x;
    if (e >= E) return;
    int s = lde<I64>(ei, (size_t)e);
    int d = lde<I64>(ei, (size_t)E + e);
    float norm = dinv[s] * dinv[d];
    atomicAdd(&a2[(size_t)d * 2 + 0], h2[(size_t)s * 2 + 0] * norm);
    atomicAdd(&a2[(size_t)d * 2 + 1], h2[(size_t)s * 2 + 1] * norm);
}
__global__ void fb_gemm1(const float* __restrict__ x, const float* __restrict__ W1,
                         float* __restrict__ h1, int n) {
    __shared__ float w[D_IN * D_HID];
    for (int i = threadIdx.x; i < D_IN * D_HID; i += blockDim.x) w[i] = W1[i];
    __syncthreads();
    int tid = blockIdx.x * blockDim.x + threadIdx.x;
    int node = tid >> 4, f = tid & 15;
    if (node >= n) return;
    const float4* xr = (const float4*)(x + (size_t)node * D_IN);
    float acc = 0.f;
#pragma unroll
    for (int k4 = 0; k4 < D_IN / 4; ++k4) {
        float4 v = xr[k4];
        int k = k4 * 4;
        acc += v.x * w[(k + 0) * D_HID + f];
        acc += v.y * w[(k + 1) * D_HID + f];
        acc += v.z * w[(k + 2) * D_HID + f];
        acc += v.w * w[(k + 3) * D_HID + f];
    }
    h1[tid] = acc;
}
__global__ void fb_lsm(const float* __restrict__ a2, float* __restrict__ out, int n) {
    int node = blockIdx.x * blockDim.x + threadIdx.x;
    if (node >= n) return;
    float v0 = a2[(size_t)node * 2 + 0];
    float v1 = a2[(size_t)node * 2 + 1];
    float m = fmaxf(v0, v1);
    float lse = m + logf(expf(v0 - m) + expf(v1 - m));
    out[(size_t)node * 2 + 0] = v0 - lse;
    out[(size_t)node * 2 + 1] = v1 - lse;
}

extern "C" void kernel_launch(void* const* d_in, const int* in_sizes, int n_in,
                              void* d_out, int out_size, void* d_ws, size_t ws_size,
                              hipStream_t stream) {
    const float* x  = (const float*)d_in[0];
    const void*  ei = d_in[1];
    const float* W1 = (const float*)d_in[2];
    const float* b1 = (const float*)d_in[3];
    const float* W2 = (const float*)d_in[4];
    const float* b2 = (const float*)d_in[5];

    const int N = in_sizes[0] / D_IN;      // 100000
    const int E = in_sizes[1] / 2;         // 3200000
    const int nb = (N + NPB - 1) / NPB;    // 391

    // fixed per-bucket capacity: 2x mean count + sentinel room, rounded to 256
    int cap = ((2 * (E / nb + 1) + NPB) + 255) & ~255;
    if (cap < 1024) cap = 1024;

    const int B = 256;
    dim3 blk(B);
    const int nBlkN = (N + B - 1) / B;
    const int nBlkE = (E + B - 1) / B;
    char* ws = (char*)d_ws;

    // ---- workspace layout (bytes) ----
    auto al = [](size_t v) { return (v + 255) & ~(size_t)255; };
    const size_t oDinv   = 0;                                       // N f32
    const size_t oDmeta  = al(oDinv + (size_t)N * 4);               // nb*NPB u32
    const size_t oGcur   = al(oDmeta + (size_t)nb * NPB * 4);       // MAXB u32
    const size_t oFlag   = al(oGcur + (size_t)MAXB * 4);            // 2 int
    const size_t oStage  = al(oFlag + 8);                           // nb*cap u32
    const size_t oStage2 = al(oStage + (size_t)nb * cap * 4);       // nb*cap u32
    const size_t oG1h    = al(oStage2 + (size_t)nb * cap * 4);      // N*16 half
    const size_t oG2     = al(oG1h + (size_t)N * D_HID * 2);        // N*2 f32
    const size_t needNew = al(oG2 + (size_t)N * 2 * 4);             // ~56 MB

    if (ws_size >= needNew && nb <= MAXB && cap <= 65280 && N < (1 << 24) - NPB) {
        float*        dinv    = (float*)(ws + oDinv);
        unsigned int* dmeta   = (unsigned int*)(ws + oDmeta);
        unsigned int* gcur    = (unsigned int*)(ws + oGcur);
        unsigned int* staged  = (unsigned int*)(ws + oStage);
        unsigned int* staged2 = (unsigned int*)(ws + oStage2);
        __half*       g1h     = (__half*)(ws + oG1h);
        float2*       g2      = (float2*)(ws + oG2);

        hipMemsetAsync(gcur, 0, (size_t)nb * 4, stream);

        dim3 gPart((E + TILE - 1) / TILE);
        k_part<<<gPart, dim3(512), 0, stream>>>(ei, gcur, staged, E, cap);

        k_sortd<<<dim3(nb, 2), dim3(512), 0, stream>>>(staged, gcur, staged2, dmeta,
                                                       dinv, cap, N);

        k_gemm1m<<<dim3((N + 63) / 64), dim3(256), 0, stream>>>(x, W1, dinv, g1h, N);

        k_agg1w<<<dim3(nb, 8), dim3(256), 0, stream>>>(staged2, dmeta, g1h, b1, W2, g2, N, cap);

        k_agg2w<<<dim3(nb, 8), dim3(256), 0, stream>>>(staged2, dmeta, g2, b2,
                                                       (float2*)d_out, N, cap);
    } else {
        // fallback: atomic path (needs ~14.8 MB)
        float* dinv  = (float*)(ws + 0);
        float* h1    = (float*)(ws + 400128);
        float* a1    = (float*)(ws + 6800256);
        float* h2    = (float*)(ws + 13200384);
        float* a2    = (float*)(ws + 14000512);
        int*   flags = (int*)  (ws + 14800640);

        k_detect<<<dim3(1), blk, 0, stream>>>((const int*)ei, flags);
        fb_deg_init<<<dim3(nBlkN), blk, 0, stream>>>((unsigned int*)dinv, N);
        fb_deg_count<false><<<dim3(nBlkE), blk, 0, stream>>>(ei, (unsigned int*)dinv, E, flags);
        fb_deg_count<true ><<<dim3(nBlkE), blk, 0, stream>>>(ei, (unsigned int*)dinv, E, flags);
        fb_dinv_inplace<<<dim3(nBlkN), blk, 0, stream>>>(dinv, N);

        dim3 g_nh((N * D_HID + B - 1) / B);
        fb_gemm1<<<g_nh, blk, 0, stream>>>(x, W1, h1, N);
        fb_a1_init<<<g_nh, blk, 0, stream>>>(h1, dinv, b1, a1, N);
        dim3 g_eh(((size_t)E * D_HID + B - 1) / B);
        fb_agg1<false><<<g_eh, blk, 0, stream>>>(ei, dinv, h1, a1, E, flags);
        fb_agg1<true ><<<g_eh, blk, 0, stream>>>(ei, dinv, h1, a1, E, flags);
        fb_relu_gemm2<<<dim3(nBlkN), blk, 0, stream>>>(a1, W2, h2, N);
        dim3 g_n2((N * N_CLS + B - 1) / B);
        fb_a2_init<<<g_n2, blk, 0, stream>>>(h2, dinv, b2, a2, N);
        fb_agg2<false><<<dim3(nBlkE), blk, 0, stream>>>(ei, dinv, h2, a2, E, flags);
        fb_agg2<true ><<<dim3(nBlkE), blk, 0, stream>>>(ei, dinv, h2, a2, E, flags);
        fb_lsm<<<dim3(nBlkN), blk, 0, stream>>>(a2, (float*)d_out, N);
    }
}

// Round 9
// 216.150 us; speedup vs baseline: 1.0472x; 1.0472x over previous
//
#include <hip/hip_runtime.h>
#include <hip/hip_bf16.h>
#include <hip/hip_fp16.h>

#define D_IN  128
#define D_HID 16
#define N_CLS 2
#define NPB   256          // nodes per bucket (bucket = dst >> 8)
#define MAXB  512          // max buckets (N <= 131072)
#define TILE  8192         // edges per k_part workgroup (512 thr x 16)
#define XROW  136          // padded LDS row stride (shorts)
#define LCAP  10496        // LDS edge slots in k_sortd (41 KB); bench cnt ~ 8.2K

#define FE 0   // edge_index storage: 0 = int32, 1 = int64

typedef short bf16x8 __attribute__((ext_vector_type(8)));
typedef float f32x4  __attribute__((ext_vector_type(4)));

__device__ __forceinline__ unsigned short f2bf(float f) {   // RNE float->bf16
    unsigned int u = __float_as_uint(f);
    u += 0x7FFFu + ((u >> 16) & 1u);
    return (unsigned short)(u >> 16);
}

template<bool I64>
__device__ __forceinline__ int lde(const void* p, size_t i) {
    if constexpr (I64) return (int)((const long long*)p)[i];
    else               return ((const int*)p)[i];
}

// ---------------- edge dtype detection (fallback path only) ----------------
__global__ void k_detect(const int* __restrict__ ev, int* __restrict__ flags) {
    __shared__ int sE;
    if (threadIdx.x == 0) sE = 0;
    __syncthreads();
    if (ev[2 * threadIdx.x + 1] != 0) atomicOr(&sE, 1);
    __syncthreads();
    if (threadIdx.x == 0) flags[FE] = sE ? 0 : 1;
}

// ---------------- pass 1: LDS-staged partition by bucket (fixed-cap regions) ----------------
template<bool I64>
__device__ __forceinline__ void part_body(
        const void* __restrict__ ei, unsigned int* __restrict__ gcur,
        unsigned int* __restrict__ staged, int E, int cap,
        unsigned int* sbuf, unsigned short* bbuf,
        int* hist, int* lbase, int* gb, int* wsum) {
    int tid = threadIdx.x;
    int t0 = blockIdx.x * TILE;

    hist[tid] = 0;
    __syncthreads();

    int myB[16]; unsigned int myP[16]; int myR[16];
#pragma unroll
    for (int k = 0; k < 16; ++k) {
        int e = t0 + k * 512 + tid;
        if (e < E) {
            int s = lde<I64>(ei, (size_t)e);
            int d = lde<I64>(ei, (size_t)E + e);
            int b = d >> 8;
            myB[k] = b;
            myP[k] = ((unsigned int)s << 8) | (unsigned int)(d & 255);
            myR[k] = atomicAdd(&hist[b], 1);
        } else myB[k] = -1;
    }
    __syncthreads();

    // shuffle-based scan over MAXB=512 counts
    int v = hist[tid];
    int lane = tid & 63, wv = tid >> 6;
    int s = v;
#pragma unroll
    for (int m = 1; m < 64; m <<= 1) {
        int t = __shfl_up(s, m, 64);
        if (lane >= m) s += t;
    }
    if (lane == 63) wsum[wv] = s;
    __syncthreads();
    int woff = 0;
#pragma unroll
    for (int w = 0; w < 8; ++w) if (w < wv) woff += wsum[w];
    int excl = s + woff - v;
    lbase[tid] = excl;
    int gb_ = 0;
    if (v > 0) gb_ = (int)atomicAdd(&gcur[tid], (unsigned int)v);  // relative base
    gb[tid] = gb_;
    __syncthreads();

#pragma unroll
    for (int k = 0; k < 16; ++k) {
        if (myB[k] >= 0) {
            int pos = lbase[myB[k]] + myR[k];
            sbuf[pos] = myP[k];
            bbuf[pos] = (unsigned short)myB[k];
        }
    }
    __syncthreads();

    int tot = lbase[MAXB - 1] + hist[MAXB - 1];
    for (int i = tid; i < tot; i += 512) {
        int b = bbuf[i];
        int rel = gb[b] + (i - lbase[b]);
        if (rel < cap)                           // overflow guard (degenerate inputs only)
            staged[(size_t)b * cap + rel] = sbuf[i];
    }
}

__global__ __launch_bounds__(512) void k_part(
        const void* __restrict__ ei, unsigned int* __restrict__ gcur,
        unsigned int* __restrict__ staged, int E, int cap) {
    __shared__ unsigned int sbuf[TILE];       // 32 KB
    __shared__ unsigned short bbuf[TILE];     // 16 KB
    __shared__ int hist[MAXB], lbase[MAXB], gb[MAXB];  // 6 KB
    __shared__ int wsum[8];
    __shared__ int sI64;
    int tid = threadIdx.x;
    if (tid == 0) sI64 = 1;
    __syncthreads();
    if (tid < 256 && 2 * tid + 1 < 2 * E && ((const int*)ei)[2 * tid + 1] != 0) sI64 = 0;
    __syncthreads();
    if (sI64) part_body<true >(ei, gcur, staged, E, cap, sbuf, bbuf, hist, lbase, gb, wsum);
    else      part_body<false>(ei, gcur, staged, E, cap, sbuf, bbuf, hist, lbase, gb, wsum);
}

// ---------------- pass 2: per-bucket counting sort by dst (LDS-staged) + dinv + metadata ----------------
__global__ __launch_bounds__(512) void k_sortd(
        const unsigned int* __restrict__ staged, const unsigned int* __restrict__ gcur,
        unsigned int* __restrict__ staged2, unsigned int* __restrict__ dmeta,
        float* __restrict__ dinv, int cap, int N) {
    __shared__ unsigned int ebuf[LCAP];       // 41 KB
    __shared__ unsigned int h[NPB];
    __shared__ unsigned int cur[NPB];
    __shared__ int wsum[4];
    int tid = threadIdx.x, b = blockIdx.x;
    long long s0 = (long long)b * cap;
    int cnt = (int)gcur[b];
    if (cnt > cap - NPB) cnt = cap - NPB;     // leave room for 256 sentinels
    bool inL = cnt <= LCAP;
    if (tid < NPB) h[tid] = 0u;
    __syncthreads();
    for (int i = tid; i < cnt; i += 512) {
        unsigned int p = staged[s0 + i];
        if (inL) ebuf[i] = p;
        atomicAdd(&h[p & 255], 1u);
    }
    __syncthreads();
    int v = 0, sIncl = 0;
    int lane = tid & 63, wv = tid >> 6;
    if (tid < NPB) {
        v = (int)h[tid];
        sIncl = v;
#pragma unroll
        for (int m = 1; m < 64; m <<= 1) {
            int t = __shfl_up(sIncl, m, 64);
            if (lane >= m) sIncl += t;
        }
        if (lane == 63) wsum[wv] = sIncl;
    }
    __syncthreads();
    if (tid < NPB) {
        int woff = 0;
#pragma unroll
        for (int w = 0; w < 4; ++w) if (w < wv) woff += wsum[w];
        int excl = sIncl + woff - v;
        int node = b * NPB + tid;
        int start = excl + tid;                  // +tid: one reserved sentinel slot per prior dst
        dmeta[node] = ((unsigned int)start << 16) | (unsigned int)v;  // start<<16 | deg
        cur[tid] = (unsigned int)start;
        if (node < N) dinv[node] = rsqrtf((float)(v + 1));           // +1 self loop
    }
    __syncthreads();
    for (int i = tid; i < cnt; i += 512) {
        unsigned int p = inL ? ebuf[i] : staged[s0 + i];
        unsigned int r = atomicAdd(&cur[p & 255], 1u);
        staged2[s0 + r] = p;
    }
    __syncthreads();
    if (tid < NPB) {
        unsigned int pos = cur[tid];             // = start + deg
        int node = b * NPB + tid;
        if ((int)pos < cap)
            staged2[s0 + pos] = ((unsigned int)node << 8) | (unsigned int)tid;  // sentinel self
    }
}

// ---------------- layer 1 GEMM via MFMA (split-bf16, 3 mfma/chunk ~ fp32 acc) ----------------
// hi via truncation (1 shift), lo via RNE of exact residual: err ~2^-16 rel, negligible.
__global__ __launch_bounds__(256) void k_gemm1m(
        const float* __restrict__ x, const float* __restrict__ W1,
        const float* __restrict__ dinv, __half* __restrict__ g1h, int n) {
    __shared__ short xhi[64 * XROW];
    __shared__ short xlo[64 * XROW];
    __shared__ short whi[16 * XROW];
    __shared__ short wlo[16 * XROW];
    int tid = threadIdx.x;
    int node0 = blockIdx.x * 64;

    for (int i = tid; i < D_IN * D_HID; i += 256) {
        int k = i >> 4, f = i & 15;
        float v = W1[i];
        unsigned short h = f2bf(v);
        float fh = __uint_as_float(((unsigned int)h) << 16);
        whi[f * XROW + k] = (short)h;
        wlo[f * XROW + k] = (short)f2bf(v - fh);
    }
    int limFlat = (n - node0) * D_IN;
#pragma unroll
    for (int it = 0; it < 8; ++it) {
        int flat = it * 1024 + tid * 4;
        float4 v = make_float4(0.f, 0.f, 0.f, 0.f);
        if (flat < limFlat) v = *(const float4*)(x + (size_t)node0 * D_IN + flat);
        int row = flat >> 7, k = flat & 127;
        unsigned int u0 = __float_as_uint(v.x), u1 = __float_as_uint(v.y);
        unsigned int u2 = __float_as_uint(v.z), u3 = __float_as_uint(v.w);
        unsigned short l0 = f2bf(v.x - __uint_as_float(u0 & 0xFFFF0000u));
        unsigned short l1 = f2bf(v.y - __uint_as_float(u1 & 0xFFFF0000u));
        unsigned short l2 = f2bf(v.z - __uint_as_float(u2 & 0xFFFF0000u));
        unsigned short l3 = f2bf(v.w - __uint_as_float(u3 & 0xFFFF0000u));
        int o = row * XROW + k;
        *(uint2*)(&xhi[o]) = make_uint2((u0 >> 16) | (u1 & 0xFFFF0000u),
                                        (u2 >> 16) | (u3 & 0xFFFF0000u));
        *(uint2*)(&xlo[o]) = make_uint2((unsigned int)l0 | ((unsigned int)l1 << 16),
                                        (unsigned int)l2 | ((unsigned int)l3 << 16));
    }
    __syncthreads();

    int w = tid >> 6, L = tid & 63;
    int m = L & 15, q = L >> 4;
    const short* axh = &xhi[(w * 16 + m) * XROW + q * 8];
    const short* axl = &xlo[(w * 16 + m) * XROW + q * 8];
    const short* bwh = &whi[m * XROW + q * 8];
    const short* bwl = &wlo[m * XROW + q * 8];
    f32x4 acc = {0.f, 0.f, 0.f, 0.f};
#pragma unroll
    for (int c = 0; c < 4; ++c) {
        bf16x8 ah = *(const bf16x8*)(axh + c * 32);
        bf16x8 al = *(const bf16x8*)(axl + c * 32);
        bf16x8 bh = *(const bf16x8*)(bwh + c * 32);
        bf16x8 bl = *(const bf16x8*)(bwl + c * 32);
        acc = __builtin_amdgcn_mfma_f32_16x16x32_bf16(ah, bh, acc, 0, 0, 0);
        acc = __builtin_amdgcn_mfma_f32_16x16x32_bf16(ah, bl, acc, 0, 0, 0);
        acc = __builtin_amdgcn_mfma_f32_16x16x32_bf16(al, bh, acc, 0, 0, 0);
    }
    int nodeB = node0 + w * 16 + q * 4;
#pragma unroll
    for (int r = 0; r < 4; ++r) {
        int node = nodeB + r;
        if (node < n) g1h[(size_t)node * D_HID + m] = __float2half(dinv[node] * acc[r]);
    }
}

// ---------------- layer-1 aggregation: clamped straight-line batched gathers ----------------
// unroll 4 over dsts: 4 x 16 independent mem ops in flight per wave (VGPR stays <= 64).
__global__ __launch_bounds__(256) void k_agg1w(
        const unsigned int* __restrict__ staged2, const unsigned int* __restrict__ dmeta,
        const __half* __restrict__ g1h,
        const float* __restrict__ b1, const float* __restrict__ W2,
        float2* __restrict__ g2, int N, int cap) {
    int tid = threadIdx.x, b = blockIdx.x, by = blockIdx.y;
    long long s0 = (long long)b * cap;
    int lane = tid & 63;
    int f2 = lane & 7;
    int e8 = lane >> 3;
    int wid = (by << 2) + (tid >> 6);        // wave id in bucket: 0..31
    const __half2* g1h2 = (const __half2*)g1h;
    int f0 = f2 * 2;
    float b10 = b1[f0], b11 = b1[f0 + 1];
    float w00 = W2[f0 * N_CLS + 0], w01 = W2[f0 * N_CLS + 1];
    float w10 = W2[(f0 + 1) * N_CLS + 0], w11 = W2[(f0 + 1) * N_CLS + 1];
    unsigned int md[8];
#pragma unroll
    for (int k = 0; k < 8; ++k) md[k] = dmeta[b * NPB + wid + (k << 5)];
#pragma unroll 4
    for (int k = 0; k < 8; ++k) {
        int node = b * NPB + wid + (k << 5);
        const unsigned int* sp = staged2 + s0 + (md[k] >> 16);
        int cnt = (int)(md[k] & 0xFFFFu) + 1;    // + sentinel self edge
        float ax = 0.f, ay = 0.f;
        for (int base = 0; base < cnt; base += 64) {
            unsigned int pe[8];
#pragma unroll
            for (int j = 0; j < 8; ++j) {        // phase 1: 8 independent loads (clamped)
                int idx = base + (j << 3) + e8;
                int c = idx < cnt ? idx : cnt - 1;
                pe[j] = sp[c];
            }
#pragma unroll
            for (int j = 0; j < 8; ++j) {        // phase 2+3: 8 independent gathers, masked acc
                int idx = base + (j << 3) + e8;
                float2 t = __half22float2(g1h2[(size_t)(pe[j] >> 8) * 8 + f2]);
                if (idx < cnt) { ax += t.x; ay += t.y; }
            }
        }
        // reduce over edge slots (lane bits 3..5)
        ax += __shfl_xor(ax, 8, 64);  ay += __shfl_xor(ay, 8, 64);
        ax += __shfl_xor(ax, 16, 64); ay += __shfl_xor(ay, 16, 64);
        ax += __shfl_xor(ax, 32, 64); ay += __shfl_xor(ay, 32, 64);
        float di = rsqrtf((float)cnt);           // == dinv[node] (cnt = deg+1)
        float r0 = fmaxf(b10 + di * ax, 0.f);
        float r1 = fmaxf(b11 + di * ay, 0.f);
        float c0 = r0 * w00 + r1 * w10;
        float c1 = r0 * w01 + r1 * w11;
        // reduce over feature pairs (lane bits 0..2)
        c0 += __shfl_xor(c0, 1, 64); c1 += __shfl_xor(c1, 1, 64);
        c0 += __shfl_xor(c0, 2, 64); c1 += __shfl_xor(c1, 2, 64);
        c0 += __shfl_xor(c0, 4, 64); c1 += __shfl_xor(c1, 4, 64);
        if (lane == 0 && node < N) g2[node] = make_float2(di * c0, di * c1);
    }
}

// ---------------- layer-2 aggregation + log_softmax: clamped full-wave gather ----------------
// unroll 4 over dsts: 4 independent load+gather chains in flight per wave.
__global__ __launch_bounds__(256) void k_agg2w(
        const unsigned int* __restrict__ staged2, const unsigned int* __restrict__ dmeta,
        const float2* __restrict__ g2,
        const float* __restrict__ b2, float2* __restrict__ out, int N, int cap) {
    int tid = threadIdx.x, b = blockIdx.x, by = blockIdx.y;
    long long s0 = (long long)b * cap;
    int lane = tid & 63;
    int wid = (by << 2) + (tid >> 6);        // 0..31
    float bb0 = b2[0], bb1 = b2[1];
    unsigned int md[8];
#pragma unroll
    for (int k = 0; k < 8; ++k) md[k] = dmeta[b * NPB + wid + (k << 5)];
#pragma unroll 4
    for (int k = 0; k < 8; ++k) {
        int node = b * NPB + wid + (k << 5);
        const unsigned int* sp = staged2 + s0 + (md[k] >> 16);
        int cnt = (int)(md[k] & 0xFFFFu) + 1;    // + sentinel self edge
        float a0 = 0.f, a1 = 0.f;
        for (int base = 0; base < cnt; base += 64) {
            int idx = base + lane;
            int c = idx < cnt ? idx : cnt - 1;
            unsigned int p = sp[c];
            float2 t = g2[p >> 8];
            if (idx < cnt) { a0 += t.x; a1 += t.y; }
        }
#pragma unroll
        for (int mm = 1; mm < 64; mm <<= 1) {
            a0 += __shfl_xor(a0, mm, 64);
            a1 += __shfl_xor(a1, mm, 64);
        }
        if (lane == 0 && node < N) {
            float di = rsqrtf((float)cnt);       // == dinv[node]
            float v0 = bb0 + di * a0;
            float v1 = bb1 + di * a1;
            float mx = fmaxf(v0, v1);
            float lse = mx + logf(expf(v0 - mx) + expf(v1 - mx));
            out[node] = make_float2(v0 - lse, v1 - lse);
        }
    }
}

// =================== fallback (atomic path, if ws too small) ===================
__global__ void fb_deg_init(unsigned int* __restrict__ deg, int n) {
    int i = blockIdx.x * blockDim.x + threadIdx.x;
    if (i < n) deg[i] = 1u;
}
template<bool I64>
__global__ void fb_deg_count(const void* __restrict__ ei, unsigned int* __restrict__ deg,
                             int E, const int* __restrict__ flags) {
    if (flags[FE] != (int)I64) return;
    int e = blockIdx.x * blockDim.x + threadIdx.x;
    if (e < E) atomicAdd(&deg[lde<I64>(ei, (size_t)E + e)], 1u);
}
__global__ void fb_dinv_inplace(float* __restrict__ dinv, int n) {
    int i = blockIdx.x * blockDim.x + threadIdx.x;
    if (i < n) {
        unsigned int u = ((const unsigned int*)dinv)[i];
        dinv[i] = rsqrtf((float)u);
    }
}
__global__ void fb_a1_init(const float* __restrict__ h1, const float* __restrict__ dinv,
                           const float* __restrict__ b1, float* __restrict__ a1, int n) {
    int tid = blockIdx.x * blockDim.x + threadIdx.x;
    if (tid >= n * D_HID) return;
    int node = tid >> 4, f = tid & 15;
    float di = dinv[node];
    a1[tid] = b1[f] + di * di * h1[tid];
}
template<bool I64>
__global__ void fb_agg1(const void* __restrict__ ei, const float* __restrict__ dinv,
                        const float* __restrict__ h1, float* __restrict__ a1,
                        int E, const int* __restrict__ flags) {
    if (flags[FE] != (int)I64) return;
    int tid = blockIdx.x * blockDim.x + threadIdx.x;
    int e = tid >> 4, f = tid & 15;
    if (e >= E) return;
    int s = lde<I64>(ei, (size_t)e);
    int d = lde<I64>(ei, (size_t)E + e);
    float norm = dinv[s] * dinv[d];
    atomicAdd(&a1[(size_t)d * D_HID + f], h1[(size_t)s * D_HID + f] * norm);
}
__global__ void fb_relu_gemm2(const float* __restrict__ a1, const float* __restrict__ W2,
                              float* __restrict__ h2, int n) {
    int node = blockIdx.x * blockDim.x + threadIdx.x;
    if (node >= n) return;
    float c0 = 0.f, c1 = 0.f;
    const float* row = a1 + (size_t)node * D_HID;
#pragma unroll
    for (int f = 0; f < D_HID; ++f) {
        float r = fmaxf(row[f], 0.f);
        c0 += r * W2[f * N_CLS + 0];
        c1 += r * W2[f * N_CLS + 1];
    }
    h2[(size_t)node * 2 + 0] = c0;
    h2[(size_t)node * 2 + 1] = c1;
}
__global__ void fb_a2_init(const float* __restrict__ h2, const float* __restrict__ dinv,
                           const float* __restrict__ b2, float* __restrict__ a2, int n) {
    int tid = blockIdx.x * blockDim.x + threadIdx.x;
    if (tid >= n * N_CLS) return;
    int node = tid >> 1, c = tid & 1;
    float di = dinv[node];
    a2[tid] = b2[c] + di * di * h2[tid];
}
template<bool I64>
__global__ void fb_agg2(const void* __restrict__ ei, const float* __restrict__ dinv,
                        const float* __restrict__ h2, float* __restrict__ a2,
                        int E, const int* __restrict__ flags) {
    if (flags[FE] != (int)I64) return;
    int e = blockIdx.x * blockDim.x + threadIdx.x;
    if (e >= E) return;
    int s = lde<I64>(ei, (size_t)e);
    int d = lde<I64>(ei, (size_t)E + e);
    float norm = dinv[s] * dinv[d];
    atomicAdd(&a2[(size_t)d * 2 + 0], h2[(size_t)s * 2 + 0] * norm);
    atomicAdd(&a2[(size_t)d * 2 + 1], h2[(size_t)s * 2 + 1] * norm);
}
__global__ void fb_gemm1(const float* __restrict__ x, const float* __restrict__ W1,
                         float* __restrict__ h1, int n) {
    __shared__ float w[D_IN * D_HID];
    for (int i = threadIdx.x; i < D_IN * D_HID; i += blockDim.x) w[i] = W1[i];
    __syncthreads();
    int tid = blockIdx.x * blockDim.x + threadIdx.x;
    int node = tid >> 4, f = tid & 15;
    if (node >= n) return;
    const float4* xr = (const float4*)(x + (size_t)node * D_IN);
    float acc = 0.f;
#pragma unroll
    for (int k4 = 0; k4 < D_IN / 4; ++k4) {
        float4 v = xr[k4];
        int k = k4 * 4;
        acc += v.x * w[(k + 0) * D_HID + f];
        acc += v.y * w[(k + 1) * D_HID + f];
        acc += v.z * w[(k + 2) * D_HID + f];
        acc += v.w * w[(k + 3) * D_HID + f];
    }
    h1[tid] = acc;
}
__global__ void fb_lsm(const float* __restrict__ a2, float* __restrict__ out, int n) {
    int node = blockIdx.x * blockDim.x + threadIdx.x;
    if (node >= n) return;
    float v0 = a2[(size_t)node * 2 + 0];
    float v1 = a2[(size_t)node * 2 + 1];
    float m = fmaxf(v0, v1);
    float lse = m + logf(expf(v0 - m) + expf(v1 - m));
    out[(size_t)node * 2 + 0] = v0 - lse;
    out[(size_t)node * 2 + 1] = v1 - lse;
}

extern "C" void kernel_launch(void* const* d_in, const int* in_sizes, int n_in,
                              void* d_out, int out_size, void* d_ws, size_t ws_size,
                              hipStream_t stream) {
    const float* x  = (const float*)d_in[0];
    const void*  ei = d_in[1];
    const float* W1 = (const float*)d_in[2];
    const float* b1 = (const float*)d_in[3];
    const float* W2 = (const float*)d_in[4];
    const float* b2 = (const float*)d_in[5];

    const int N = in_sizes[0] / D_IN;      // 100000
    const int E = in_sizes[1] / 2;         // 3200000
    const int nb = (N + NPB - 1) / NPB;    // 391

    // fixed per-bucket capacity: 2x mean count + sentinel room, rounded to 256
    int cap = ((2 * (E / nb + 1) + NPB) + 255) & ~255;
    if (cap < 1024) cap = 1024;

    const int B = 256;
    dim3 blk(B);
    const int nBlkN = (N + B - 1) / B;
    const int nBlkE = (E + B - 1) / B;
    char* ws = (char*)d_ws;

    // ---- workspace layout (bytes) ----
    auto al = [](size_t v) { return (v + 255) & ~(size_t)255; };
    const size_t oDinv   = 0;                                       // N f32
    const size_t oDmeta  = al(oDinv + (size_t)N * 4);               // nb*NPB u32
    const size_t oGcur   = al(oDmeta + (size_t)nb * NPB * 4);       // MAXB u32
    const size_t oFlag   = al(oGcur + (size_t)MAXB * 4);            // 2 int
    const size_t oStage  = al(oFlag + 8);                           // nb*cap u32
    const size_t oStage2 = al(oStage + (size_t)nb * cap * 4);       // nb*cap u32
    const size_t oG1h    = al(oStage2 + (size_t)nb * cap * 4);      // N*16 half
    const size_t oG2     = al(oG1h + (size_t)N * D_HID * 2);        // N*2 f32
    const size_t needNew = al(oG2 + (size_t)N * 2 * 4);             // ~56 MB

    if (ws_size >= needNew && nb <= MAXB && cap <= 65280 && N < (1 << 24) - NPB) {
        float*        dinv    = (float*)(ws + oDinv);
        unsigned int* dmeta   = (unsigned int*)(ws + oDmeta);
        unsigned int* gcur    = (unsigned int*)(ws + oGcur);
        unsigned int* staged  = (unsigned int*)(ws + oStage);
        unsigned int* staged2 = (unsigned int*)(ws + oStage2);
        __half*       g1h     = (__half*)(ws + oG1h);
        float2*       g2      = (float2*)(ws + oG2);

        hipMemsetAsync(gcur, 0, (size_t)nb * 4, stream);

        dim3 gPart((E + TILE - 1) / TILE);
        k_part<<<gPart, dim3(512), 0, stream>>>(ei, gcur, staged, E, cap);

        k_sortd<<<dim3(nb), dim3(512), 0, stream>>>(staged, gcur, staged2, dmeta, dinv, cap, N);

        k_gemm1m<<<dim3((N + 63) / 64), dim3(256), 0, stream>>>(x, W1, dinv, g1h, N);

        k_agg1w<<<dim3(nb, 8), dim3(256), 0, stream>>>(staged2, dmeta, g1h, b1, W2, g2, N, cap);

        k_agg2w<<<dim3(nb, 8), dim3(256), 0, stream>>>(staged2, dmeta, g2, b2,
                                                       (float2*)d_out, N, cap);
    } else {
        // fallback: atomic path (needs ~14.8 MB)
        float* dinv  = (float*)(ws + 0);
        float* h1    = (float*)(ws + 400128);
        float* a1    = (float*)(ws + 6800256);
        float* h2    = (float*)(ws + 13200384);
        float* a2    = (float*)(ws + 14000512);
        int*   flags = (int*)  (ws + 14800640);

        k_detect<<<dim3(1), blk, 0, stream>>>((const int*)ei, flags);
        fb_deg_init<<<dim3(nBlkN), blk, 0, stream>>>((unsigned int*)dinv, N);
        fb_deg_count<false><<<dim3(nBlkE), blk, 0, stream>>>(ei, (unsigned int*)dinv, E, flags);
        fb_deg_count<true ><<<dim3(nBlkE), blk, 0, stream>>>(ei, (unsigned int*)dinv, E, flags);
        fb_dinv_inplace<<<dim3(nBlkN), blk, 0, stream>>>(dinv, N);

        dim3 g_nh((N * D_HID + B - 1) / B);
        fb_gemm1<<<g_nh, blk, 0, stream>>>(x, W1, h1, N);
        fb_a1_init<<<g_nh, blk, 0, stream>>>(h1, dinv, b1, a1, N);
        dim3 g_eh(((size_t)E * D_HID + B - 1) / B);
        fb_agg1<false><<<g_eh, blk, 0, stream>>>(ei, dinv, h1, a1, E, flags);
        fb_agg1<true ><<<g_eh, blk, 0, stream>>>(ei, dinv, h1, a1, E, flags);
        fb_relu_gemm2<<<dim3(nBlkN), blk, 0, stream>>>(a1, W2, h2, N);
        dim3 g_n2((N * N_CLS + B - 1) / B);
        fb_a2_init<<<g_n2, blk, 0, stream>>>(h2, dinv, b2, a2, N);
        fb_agg2<false><<<dim3(nBlkE), blk, 0, stream>>>(ei, dinv, h2, a2, E, flags);
        fb_agg2<true ><<<dim3(nBlkE), blk, 0, stream>>>(ei, dinv, h2, a2, E, flags);
        fb_lsm<<<dim3(nBlkN), blk, 0, stream>>>(a2, (float*)d_out, N);
    }
}

// Round 10
// 212.663 us; speedup vs baseline: 1.0644x; 1.0164x over previous
//
#include <hip/hip_runtime.h>
#include <hip/hip_bf16.h>
#include <hip/hip_fp16.h>

#define D_IN  128
#define D_HID 16
#define N_CLS 2
#define NPB   256          // nodes per bucket (bucket = dst >> 8)
#define MAXB  512          // max buckets (N <= 131072)
#define TILE  8192         // edges per k_part workgroup (1024 thr x 8)
#define XROW  136          // padded LDS row stride (shorts)
#define LCAP  10496        // LDS edge slots in k_sortd (41 KB); bench cnt ~ 8.2K

#define FE 0   // edge_index storage: 0 = int32, 1 = int64

typedef short bf16x8 __attribute__((ext_vector_type(8)));
typedef float f32x4  __attribute__((ext_vector_type(4)));

__device__ __forceinline__ unsigned short f2bf(float f) {   // RNE float->bf16
    unsigned int u = __float_as_uint(f);
    u += 0x7FFFu + ((u >> 16) & 1u);
    return (unsigned short)(u >> 16);
}

template<bool I64>
__device__ __forceinline__ int lde(const void* p, size_t i) {
    if constexpr (I64) return (int)((const long long*)p)[i];
    else               return ((const int*)p)[i];
}

// ---------------- edge dtype detection (fallback path only) ----------------
__global__ void k_detect(const int* __restrict__ ev, int* __restrict__ flags) {
    __shared__ int sE;
    if (threadIdx.x == 0) sE = 0;
    __syncthreads();
    if (ev[2 * threadIdx.x + 1] != 0) atomicOr(&sE, 1);
    __syncthreads();
    if (threadIdx.x == 0) flags[FE] = sE ? 0 : 1;
}

// ---------------- pass 1: LDS-staged partition by bucket (1024 thr, 8 items/thr) ----------------
template<bool I64>
__device__ __forceinline__ void part_body(
        const void* __restrict__ ei, unsigned int* __restrict__ gcur,
        unsigned int* __restrict__ staged, int E, int cap,
        unsigned int* sbuf, unsigned short* bbuf,
        int* hist, int* lbase, int* gb, int* wsum) {
    int tid = threadIdx.x;
    int t0 = blockIdx.x * TILE;

    if (tid < MAXB) hist[tid] = 0;
    __syncthreads();

    int myB[8]; unsigned int myP[8]; int myR[8];
#pragma unroll
    for (int k = 0; k < 8; ++k) {
        int e = t0 + k * 1024 + tid;
        if (e < E) {
            int s = lde<I64>(ei, (size_t)e);
            int d = lde<I64>(ei, (size_t)E + e);
            int b = d >> 8;
            myB[k] = b;
            myP[k] = ((unsigned int)s << 8) | (unsigned int)(d & 255);
            myR[k] = atomicAdd(&hist[b], 1);
        } else myB[k] = -1;
    }
    __syncthreads();

    // shuffle-based scan over MAXB=512 counts (waves 0..7)
    int lane = tid & 63, wv = tid >> 6;
    int v = 0, s = 0;
    if (tid < MAXB) {
        v = hist[tid];
        s = v;
#pragma unroll
        for (int m = 1; m < 64; m <<= 1) {
            int t = __shfl_up(s, m, 64);
            if (lane >= m) s += t;
        }
        if (lane == 63) wsum[wv] = s;
    }
    __syncthreads();
    if (tid < MAXB) {
        int woff = 0;
#pragma unroll
        for (int w = 0; w < 8; ++w) if (w < wv) woff += wsum[w];
        int excl = s + woff - v;
        lbase[tid] = excl;
        int gb_ = 0;
        if (v > 0) gb_ = (int)atomicAdd(&gcur[tid], (unsigned int)v);  // relative base
        gb[tid] = gb_;
    }
    __syncthreads();

#pragma unroll
    for (int k = 0; k < 8; ++k) {
        if (myB[k] >= 0) {
            int pos = lbase[myB[k]] + myR[k];
            sbuf[pos] = myP[k];
            bbuf[pos] = (unsigned short)myB[k];
        }
    }
    __syncthreads();

    int tot = lbase[MAXB - 1] + hist[MAXB - 1];
    for (int i = tid; i < tot; i += 1024) {
        int b = bbuf[i];
        int rel = gb[b] + (i - lbase[b]);
        if (rel < cap)                           // overflow guard (degenerate inputs only)
            staged[(size_t)b * cap + rel] = sbuf[i];
    }
}

__global__ __launch_bounds__(1024) void k_part(
        const void* __restrict__ ei, unsigned int* __restrict__ gcur,
        unsigned int* __restrict__ staged, int E, int cap) {
    __shared__ unsigned int sbuf[TILE];       // 32 KB
    __shared__ unsigned short bbuf[TILE];     // 16 KB
    __shared__ int hist[MAXB], lbase[MAXB], gb[MAXB];  // 6 KB
    __shared__ int wsum[8];
    __shared__ int sI64;
    int tid = threadIdx.x;
    if (tid == 0) sI64 = 1;
    __syncthreads();
    if (tid < 256 && 2 * tid + 1 < 2 * E && ((const int*)ei)[2 * tid + 1] != 0) sI64 = 0;
    __syncthreads();
    if (sI64) part_body<true >(ei, gcur, staged, E, cap, sbuf, bbuf, hist, lbase, gb, wsum);
    else      part_body<false>(ei, gcur, staged, E, cap, sbuf, bbuf, hist, lbase, gb, wsum);
}

// ---------------- pass 2: per-bucket counting sort by dst (LDS-staged, 1024 thr) ----------------
__global__ __launch_bounds__(1024) void k_sortd(
        const unsigned int* __restrict__ staged, const unsigned int* __restrict__ gcur,
        unsigned int* __restrict__ staged2, unsigned int* __restrict__ dmeta,
        float* __restrict__ dinv, int cap, int N) {
    __shared__ unsigned int ebuf[LCAP];       // 41 KB
    __shared__ unsigned int h[NPB];
    __shared__ unsigned int cur[NPB];
    __shared__ int wsum[4];
    int tid = threadIdx.x, b = blockIdx.x;
    long long s0 = (long long)b * cap;
    int cnt = (int)gcur[b];
    if (cnt > cap - NPB) cnt = cap - NPB;     // leave room for 256 sentinels
    bool inL = cnt <= LCAP;
    if (tid < NPB) h[tid] = 0u;
    __syncthreads();
    for (int i = tid; i < cnt; i += 1024) {
        unsigned int p = staged[s0 + i];
        if (inL) ebuf[i] = p;
        atomicAdd(&h[p & 255], 1u);
    }
    __syncthreads();
    int v = 0, sIncl = 0;
    int lane = tid & 63, wv = tid >> 6;
    if (tid < NPB) {
        v = (int)h[tid];
        sIncl = v;
#pragma unroll
        for (int m = 1; m < 64; m <<= 1) {
            int t = __shfl_up(sIncl, m, 64);
            if (lane >= m) sIncl += t;
        }
        if (lane == 63) wsum[wv] = sIncl;
    }
    __syncthreads();
    if (tid < NPB) {
        int woff = 0;
#pragma unroll
        for (int w = 0; w < 4; ++w) if (w < wv) woff += wsum[w];
        int excl = sIncl + woff - v;
        int node = b * NPB + tid;
        int start = excl + tid;                  // +tid: one reserved sentinel slot per prior dst
        dmeta[node] = ((unsigned int)start << 16) | (unsigned int)v;  // start<<16 | deg
        cur[tid] = (unsigned int)start;
        if (node < N) dinv[node] = rsqrtf((float)(v + 1));           // +1 self loop
    }
    __syncthreads();
    for (int i = tid; i < cnt; i += 1024) {
        unsigned int p = inL ? ebuf[i] : staged[s0 + i];
        unsigned int r = atomicAdd(&cur[p & 255], 1u);
        staged2[s0 + r] = p;
    }
    __syncthreads();
    if (tid < NPB) {
        unsigned int pos = cur[tid];             // = start + deg
        int node = b * NPB + tid;
        if ((int)pos < cap)
            staged2[s0 + pos] = ((unsigned int)node << 8) | (unsigned int)tid;  // sentinel self
    }
}

// ---------------- layer 1 GEMM via MFMA (split-bf16, 3 mfma/chunk ~ fp32 acc) ----------------
// hi via truncation (1 shift), lo via RNE of exact residual: err ~2^-16 rel, negligible.
__global__ __launch_bounds__(256) void k_gemm1m(
        const float* __restrict__ x, const float* __restrict__ W1,
        const float* __restrict__ dinv, __half* __restrict__ g1h, int n) {
    __shared__ short xhi[64 * XROW];
    __shared__ short xlo[64 * XROW];
    __shared__ short whi[16 * XROW];
    __shared__ short wlo[16 * XROW];
    int tid = threadIdx.x;
    int node0 = blockIdx.x * 64;

    for (int i = tid; i < D_IN * D_HID; i += 256) {
        int k = i >> 4, f = i & 15;
        float v = W1[i];
        unsigned short h = f2bf(v);
        float fh = __uint_as_float(((unsigned int)h) << 16);
        whi[f * XROW + k] = (short)h;
        wlo[f * XROW + k] = (short)f2bf(v - fh);
    }
    int limFlat = (n - node0) * D_IN;
#pragma unroll
    for (int it = 0; it < 8; ++it) {
        int flat = it * 1024 + tid * 4;
        float4 v = make_float4(0.f, 0.f, 0.f, 0.f);
        if (flat < limFlat) v = *(const float4*)(x + (size_t)node0 * D_IN + flat);
        int row = flat >> 7, k = flat & 127;
        unsigned int u0 = __float_as_uint(v.x), u1 = __float_as_uint(v.y);
        unsigned int u2 = __float_as_uint(v.z), u3 = __float_as_uint(v.w);
        unsigned short l0 = f2bf(v.x - __uint_as_float(u0 & 0xFFFF0000u));
        unsigned short l1 = f2bf(v.y - __uint_as_float(u1 & 0xFFFF0000u));
        unsigned short l2 = f2bf(v.z - __uint_as_float(u2 & 0xFFFF0000u));
        unsigned short l3 = f2bf(v.w - __uint_as_float(u3 & 0xFFFF0000u));
        int o = row * XROW + k;
        *(uint2*)(&xhi[o]) = make_uint2((u0 >> 16) | (u1 & 0xFFFF0000u),
                                        (u2 >> 16) | (u3 & 0xFFFF0000u));
        *(uint2*)(&xlo[o]) = make_uint2((unsigned int)l0 | ((unsigned int)l1 << 16),
                                        (unsigned int)l2 | ((unsigned int)l3 << 16));
    }
    __syncthreads();

    int w = tid >> 6, L = tid & 63;
    int m = L & 15, q = L >> 4;
    const short* axh = &xhi[(w * 16 + m) * XROW + q * 8];
    const short* axl = &xlo[(w * 16 + m) * XROW + q * 8];
    const short* bwh = &whi[m * XROW + q * 8];
    const short* bwl = &wlo[m * XROW + q * 8];
    f32x4 acc = {0.f, 0.f, 0.f, 0.f};
#pragma unroll
    for (int c = 0; c < 4; ++c) {
        bf16x8 ah = *(const bf16x8*)(axh + c * 32);
        bf16x8 al = *(const bf16x8*)(axl + c * 32);
        bf16x8 bh = *(const bf16x8*)(bwh + c * 32);
        bf16x8 bl = *(const bf16x8*)(bwl + c * 32);
        acc = __builtin_amdgcn_mfma_f32_16x16x32_bf16(ah, bh, acc, 0, 0, 0);
        acc = __builtin_amdgcn_mfma_f32_16x16x32_bf16(ah, bl, acc, 0, 0, 0);
        acc = __builtin_amdgcn_mfma_f32_16x16x32_bf16(al, bh, acc, 0, 0, 0);
    }
    int nodeB = node0 + w * 16 + q * 4;
#pragma unroll
    for (int r = 0; r < 4; ++r) {
        int node = nodeB + r;
        if (node < n) g1h[(size_t)node * D_HID + m] = __float2half(dinv[node] * acc[r]);
    }
}

// ---------------- layer-1 aggregation: clamped straight-line batched gathers ----------------
// unroll 4 over dsts: 4 x 16 independent mem ops in flight per wave (VGPR stays <= 64).
__global__ __launch_bounds__(256) void k_agg1w(
        const unsigned int* __restrict__ staged2, const unsigned int* __restrict__ dmeta,
        const __half* __restrict__ g1h,
        const float* __restrict__ b1, const float* __restrict__ W2,
        float2* __restrict__ g2, int N, int cap) {
    int tid = threadIdx.x, b = blockIdx.x, by = blockIdx.y;
    long long s0 = (long long)b * cap;
    int lane = tid & 63;
    int f2 = lane & 7;
    int e8 = lane >> 3;
    int wid = (by << 2) + (tid >> 6);        // wave id in bucket: 0..31
    const __half2* g1h2 = (const __half2*)g1h;
    int f0 = f2 * 2;
    float b10 = b1[f0], b11 = b1[f0 + 1];
    float w00 = W2[f0 * N_CLS + 0], w01 = W2[f0 * N_CLS + 1];
    float w10 = W2[(f0 + 1) * N_CLS + 0], w11 = W2[(f0 + 1) * N_CLS + 1];
    unsigned int md[8];
#pragma unroll
    for (int k = 0; k < 8; ++k) md[k] = dmeta[b * NPB + wid + (k << 5)];
#pragma unroll 4
    for (int k = 0; k < 8; ++k) {
        int node = b * NPB + wid + (k << 5);
        const unsigned int* sp = staged2 + s0 + (md[k] >> 16);
        int cnt = (int)(md[k] & 0xFFFFu) + 1;    // + sentinel self edge
        float ax = 0.f, ay = 0.f;
        for (int base = 0; base < cnt; base += 64) {
            unsigned int pe[8];
#pragma unroll
            for (int j = 0; j < 8; ++j) {        // phase 1: 8 independent loads (clamped)
                int idx = base + (j << 3) + e8;
                int c = idx < cnt ? idx : cnt - 1;
                pe[j] = sp[c];
            }
#pragma unroll
            for (int j = 0; j < 8; ++j) {        // phase 2+3: 8 independent gathers, masked acc
                int idx = base + (j << 3) + e8;
                float2 t = __half22float2(g1h2[(size_t)(pe[j] >> 8) * 8 + f2]);
                if (idx < cnt) { ax += t.x; ay += t.y; }
            }
        }
        // reduce over edge slots (lane bits 3..5)
        ax += __shfl_xor(ax, 8, 64);  ay += __shfl_xor(ay, 8, 64);
        ax += __shfl_xor(ax, 16, 64); ay += __shfl_xor(ay, 16, 64);
        ax += __shfl_xor(ax, 32, 64); ay += __shfl_xor(ay, 32, 64);
        float di = rsqrtf((float)cnt);           // == dinv[node] (cnt = deg+1)
        float r0 = fmaxf(b10 + di * ax, 0.f);
        float r1 = fmaxf(b11 + di * ay, 0.f);
        float c0 = r0 * w00 + r1 * w10;
        float c1 = r0 * w01 + r1 * w11;
        // reduce over feature pairs (lane bits 0..2)
        c0 += __shfl_xor(c0, 1, 64); c1 += __shfl_xor(c1, 1, 64);
        c0 += __shfl_xor(c0, 2, 64); c1 += __shfl_xor(c1, 2, 64);
        c0 += __shfl_xor(c0, 4, 64); c1 += __shfl_xor(c1, 4, 64);
        if (lane == 0 && node < N) g2[node] = make_float2(di * c0, di * c1);
    }
}

// ---------------- layer-2 aggregation + log_softmax: clamped full-wave gather ----------------
// unroll 4 over dsts: 4 independent load+gather chains in flight per wave.
__global__ __launch_bounds__(256) void k_agg2w(
        const unsigned int* __restrict__ staged2, const unsigned int* __restrict__ dmeta,
        const float2* __restrict__ g2,
        const float* __restrict__ b2, float2* __restrict__ out, int N, int cap) {
    int tid = threadIdx.x, b = blockIdx.x, by = blockIdx.y;
    long long s0 = (long long)b * cap;
    int lane = tid & 63;
    int wid = (by << 2) + (tid >> 6);        // 0..31
    float bb0 = b2[0], bb1 = b2[1];
    unsigned int md[8];
#pragma unroll
    for (int k = 0; k < 8; ++k) md[k] = dmeta[b * NPB + wid + (k << 5)];
#pragma unroll 4
    for (int k = 0; k < 8; ++k) {
        int node = b * NPB + wid + (k << 5);
        const unsigned int* sp = staged2 + s0 + (md[k] >> 16);
        int cnt = (int)(md[k] & 0xFFFFu) + 1;    // + sentinel self edge
        float a0 = 0.f, a1 = 0.f;
        for (int base = 0; base < cnt; base += 64) {
            int idx = base + lane;
            int c = idx < cnt ? idx : cnt - 1;
            unsigned int p = sp[c];
            float2 t = g2[p >> 8];
            if (idx < cnt) { a0 += t.x; a1 += t.y; }
        }
#pragma unroll
        for (int mm = 1; mm < 64; mm <<= 1) {
            a0 += __shfl_xor(a0, mm, 64);
            a1 += __shfl_xor(a1, mm, 64);
        }
        if (lane == 0 && node < N) {
            float di = rsqrtf((float)cnt);       // == dinv[node]
            float v0 = bb0 + di * a0;
            float v1 = bb1 + di * a1;
            float mx = fmaxf(v0, v1);
            float lse = mx + logf(expf(v0 - mx) + expf(v1 - mx));
            out[node] = make_float2(v0 - lse, v1 - lse);
        }
    }
}

// =================== fallback (atomic path, if ws too small) ===================
__global__ void fb_deg_init(unsigned int* __restrict__ deg, int n) {
    int i = blockIdx.x * blockDim.x + threadIdx.x;
    if (i < n) deg[i] = 1u;
}
template<bool I64>
__global__ void fb_deg_count(const void* __restrict__ ei, unsigned int* __restrict__ deg,
                             int E, const int* __restrict__ flags) {
    if (flags[FE] != (int)I64) return;
    int e = blockIdx.x * blockDim.x + threadIdx.x;
    if (e < E) atomicAdd(&deg[lde<I64>(ei, (size_t)E + e)], 1u);
}
__global__ void fb_dinv_inplace(float* __restrict__ dinv, int n) {
    int i = blockIdx.x * blockDim.x + threadIdx.x;
    if (i < n) {
        unsigned int u = ((const unsigned int*)dinv)[i];
        dinv[i] = rsqrtf((float)u);
    }
}
__global__ void fb_a1_init(const float* __restrict__ h1, const float* __restrict__ dinv,
                           const float* __restrict__ b1, float* __restrict__ a1, int n) {
    int tid = blockIdx.x * blockDim.x + threadIdx.x;
    if (tid >= n * D_HID) return;
    int node = tid >> 4, f = tid & 15;
    float di = dinv[node];
    a1[tid] = b1[f] + di * di * h1[tid];
}
template<bool I64>
__global__ void fb_agg1(const void* __restrict__ ei, const float* __restrict__ dinv,
                        const float* __restrict__ h1, float* __restrict__ a1,
                        int E, const int* __restrict__ flags) {
    if (flags[FE] != (int)I64) return;
    int tid = blockIdx.x * blockDim.x + threadIdx.x;
    int e = tid >> 4, f = tid & 15;
    if (e >= E) return;
    int s = lde<I64>(ei, (size_t)e);
    int d = lde<I64>(ei, (size_t)E + e);
    float norm = dinv[s] * dinv[d];
    atomicAdd(&a1[(size_t)d * D_HID + f], h1[(size_t)s * D_HID + f] * norm);
}
__global__ void fb_relu_gemm2(const float* __restrict__ a1, const float* __restrict__ W2,
                              float* __restrict__ h2, int n) {
    int node = blockIdx.x * blockDim.x + threadIdx.x;
    if (node >= n) return;
    float c0 = 0.f, c1 = 0.f;
    const float* row = a1 + (size_t)node * D_HID;
#pragma unroll
    for (int f = 0; f < D_HID; ++f) {
        float r = fmaxf(row[f], 0.f);
        c0 += r * W2[f * N_CLS + 0];
        c1 += r * W2[f * N_CLS + 1];
    }
    h2[(size_t)node * 2 + 0] = c0;
    h2[(size_t)node * 2 + 1] = c1;
}
__global__ void fb_a2_init(const float* __restrict__ h2, const float* __restrict__ dinv,
                           const float* __restrict__ b2, float* __restrict__ a2, int n) {
    int tid = blockIdx.x * blockDim.x + threadIdx.x;
    if (tid >= n * N_CLS) return;
    int node = tid >> 1, c = tid & 1;
    float di = dinv[node];
    a2[tid] = b2[c] + di * di * h2[tid];
}
template<bool I64>
__global__ void fb_agg2(const void* __restrict__ ei, const float* __restrict__ dinv,
                        const float* __restrict__ h2, float* __restrict__ a2,
                        int E, const int* __restrict__ flags) {
    if (flags[FE] != (int)I64) return;
    int e = blockIdx.x * blockDim.x + threadIdx.x;
    if (e >= E) return;
    int s = lde<I64>(ei, (size_t)e);
    int d = lde<I64>(ei, (size_t)E + e);
    float norm = dinv[s] * dinv[d];
    atomicAdd(&a2[(size_t)d * 2 + 0], h2[(size_t)s * 2 + 0] * norm);
    atomicAdd(&a2[(size_t)d * 2 + 1], h2[(size_t)s * 2 + 1] * norm);
}
__global__ void fb_gemm1(const float* __restrict__ x, const float* __restrict__ W1,
                         float* __restrict__ h1, int n) {
    __shared__ float w[D_IN * D_HID];
    for (int i = threadIdx.x; i < D_IN * D_HID; i += blockDim.x) w[i] = W1[i];
    __syncthreads();
    int tid = blockIdx.x * blockDim.x + threadIdx.x;
    int node = tid >> 4, f = tid & 15;
    if (node >= n) return;
    const float4* xr = (const float4*)(x + (size_t)node * D_IN);
    float acc = 0.f;
#pragma unroll
    for (int k4 = 0; k4 < D_IN / 4; ++k4) {
        float4 v = xr[k4];
        int k = k4 * 4;
        acc += v.x * w[(k + 0) * D_HID + f];
        acc += v.y * w[(k + 1) * D_HID + f];
        acc += v.z * w[(k + 2) * D_HID + f];
        acc += v.w * w[(k + 3) * D_HID + f];
    }
    h1[tid] = acc;
}
__global__ void fb_lsm(const float* __restrict__ a2, float* __restrict__ out, int n) {
    int node = blockIdx.x * blockDim.x + threadIdx.x;
    if (node >= n) return;
    float v0 = a2[(size_t)node * 2 + 0];
    float v1 = a2[(size_t)node * 2 + 1];
    float m = fmaxf(v0, v1);
    float lse = m + logf(expf(v0 - m) + expf(v1 - m));
    out[(size_t)node * 2 + 0] = v0 - lse;
    out[(size_t)node * 2 + 1] = v1 - lse;
}

extern "C" void kernel_launch(void* const* d_in, const int* in_sizes, int n_in,
                              void* d_out, int out_size, void* d_ws, size_t ws_size,
                              hipStream_t stream) {
    const float* x  = (const float*)d_in[0];
    const void*  ei = d_in[1];
    const float* W1 = (const float*)d_in[2];
    const float* b1 = (const float*)d_in[3];
    const float* W2 = (const float*)d_in[4];
    const float* b2 = (const float*)d_in[5];

    const int N = in_sizes[0] / D_IN;      // 100000
    const int E = in_sizes[1] / 2;         // 3200000
    const int nb = (N + NPB - 1) / NPB;    // 391

    // fixed per-bucket capacity: 2x mean count + sentinel room, rounded to 256
    int cap = ((2 * (E / nb + 1) + NPB) + 255) & ~255;
    if (cap < 1024) cap = 1024;

    const int B = 256;
    dim3 blk(B);
    const int nBlkN = (N + B - 1) / B;
    const int nBlkE = (E + B - 1) / B;
    char* ws = (char*)d_ws;

    // ---- workspace layout (bytes) ----
    auto al = [](size_t v) { return (v + 255) & ~(size_t)255; };
    const size_t oDinv   = 0;                                       // N f32
    const size_t oDmeta  = al(oDinv + (size_t)N * 4);               // nb*NPB u32
    const size_t oGcur   = al(oDmeta + (size_t)nb * NPB * 4);       // MAXB u32
    const size_t oFlag   = al(oGcur + (size_t)MAXB * 4);            // 2 int
    const size_t oStage  = al(oFlag + 8);                           // nb*cap u32
    const size_t oStage2 = al(oStage + (size_t)nb * cap * 4);       // nb*cap u32
    const size_t oG1h    = al(oStage2 + (size_t)nb * cap * 4);      // N*16 half
    const size_t oG2     = al(oG1h + (size_t)N * D_HID * 2);        // N*2 f32
    const size_t needNew = al(oG2 + (size_t)N * 2 * 4);             // ~56 MB

    if (ws_size >= needNew && nb <= MAXB && cap <= 65280 && N < (1 << 24) - NPB) {
        float*        dinv    = (float*)(ws + oDinv);
        unsigned int* dmeta   = (unsigned int*)(ws + oDmeta);
        unsigned int* gcur    = (unsigned int*)(ws + oGcur);
        unsigned int* staged  = (unsigned int*)(ws + oStage);
        unsigned int* staged2 = (unsigned int*)(ws + oStage2);
        __half*       g1h     = (__half*)(ws + oG1h);
        float2*       g2      = (float2*)(ws + oG2);

        hipMemsetAsync(gcur, 0, (size_t)nb * 4, stream);

        dim3 gPart((E + TILE - 1) / TILE);
        k_part<<<gPart, dim3(1024), 0, stream>>>(ei, gcur, staged, E, cap);

        k_sortd<<<dim3(nb), dim3(1024), 0, stream>>>(staged, gcur, staged2, dmeta, dinv, cap, N);

        k_gemm1m<<<dim3((N + 63) / 64), dim3(256), 0, stream>>>(x, W1, dinv, g1h, N);

        k_agg1w<<<dim3(nb, 8), dim3(256), 0, stream>>>(staged2, dmeta, g1h, b1, W2, g2, N, cap);

        k_agg2w<<<dim3(nb, 8), dim3(256), 0, stream>>>(staged2, dmeta, g2, b2,
                                                       (float2*)d_out, N, cap);
    } else {
        // fallback: atomic path (needs ~14.8 MB)
        float* dinv  = (float*)(ws + 0);
        float* h1    = (float*)(ws + 400128);
        float* a1    = (float*)(ws + 6800256);
        float* h2    = (float*)(ws + 13200384);
        float* a2    = (float*)(ws + 14000512);
        int*   flags = (int*)  (ws + 14800640);

        k_detect<<<dim3(1), blk, 0, stream>>>((const int*)ei, flags);
        fb_deg_init<<<dim3(nBlkN), blk, 0, stream>>>((unsigned int*)dinv, N);
        fb_deg_count<false><<<dim3(nBlkE), blk, 0, stream>>>(ei, (unsigned int*)dinv, E, flags);
        fb_deg_count<true ><<<dim3(nBlkE), blk, 0, stream>>>(ei, (unsigned int*)dinv, E, flags);
        fb_dinv_inplace<<<dim3(nBlkN), blk, 0, stream>>>(dinv, N);

        dim3 g_nh((N * D_HID + B - 1) / B);
        fb_gemm1<<<g_nh, blk, 0, stream>>>(x, W1, h1, N);
        fb_a1_init<<<g_nh, blk, 0, stream>>>(h1, dinv, b1, a1, N);
        dim3 g_eh(((size_t)E * D_HID + B - 1) / B);
        fb_agg1<false><<<g_eh, blk, 0, stream>>>(ei, dinv, h1, a1, E, flags);
        fb_agg1<true ><<<g_eh, blk, 0, stream>>>(ei, dinv, h1, a1, E, flags);
        fb_relu_gemm2<<<dim3(nBlkN), blk, 0, stream>>>(a1, W2, h2, N);
        dim3 g_n2((N * N_CLS + B - 1) / B);
        fb_a2_init<<<g_n2, blk, 0, stream>>>(h2, dinv, b2, a2, N);
        fb_agg2<false><<<dim3(nBlkE), blk, 0, stream>>>(ei, dinv, h2, a2, E, flags);
        fb_agg2<true ><<<dim3(nBlkE), blk, 0, stream>>>(ei, dinv, h2, a2, E, flags);
        fb_lsm<<<dim3(nBlkN), blk, 0, stream>>>(a2, (float*)d_out, N);
    }
}